// Round 5
// baseline (932.401 us; speedup 1.0000x reference)
//
#include <hip/hip_runtime.h>

// ---- problem constants (from reference) ----
#define NB 2
#define NT 3
#define NCAM 6
#define NC 16
#define FD 48
#define FH 24
#define FW 64
#define GX 100
#define GY 100
#define GZ 8
#define OC 40
#define NVOX (GX * GY * GZ)          // 80000
#define FSZ (FD * FH * FW)           // 73728 voxels per channel volume
#define CAMSZ (NC * FSZ)             // per-camera feature volume (orig layout)
#define BTSZ (NCAM * CAMSZ)          // per-(b,t) feature block (orig layout)
#define HSZ ((size_t)NB * NT * OC * NVOX)             // 19,200,000 elems
#define FT_ELEMS ((size_t)NB * NT * NCAM * FSZ * NC)  // 42,467,328 elems

// ----------------------------------------------------------------------------
// Setup: P[b,t,n] = intrins[b] @ RT[b,t,n][:3,:]  (3x4)
//        theta[b,t] cumulative affine (3x4): t=2 -> I, t=1 -> M4[b,1],
//        t=0 -> M4[b,0] @ M4[b,1]
// ----------------------------------------------------------------------------
__global__ void setup_kernel(const float* __restrict__ RT,
                             const float* __restrict__ intrins,
                             const float* __restrict__ DoF,
                             float* __restrict__ P,
                             float* __restrict__ theta) {
    int tid = threadIdx.x;
    if (tid < NB * NT * NCAM) {
        int bt = tid / NCAM;
        int b = bt / NT;
        const float* I3 = intrins + b * 9;
        const float* R = RT + (size_t)tid * 16;
        float* Pp = P + tid * 12;
        for (int r = 0; r < 3; ++r)
            for (int c = 0; c < 4; ++c) {
                float s = 0.f;
                for (int k = 0; k < 3; ++k) s += I3[r * 3 + k] * R[k * 4 + c];
                Pp[r * 4 + c] = s;
            }
    }
    if (tid >= 64 && tid < 64 + NB) {
        int b = tid - 64;
        const float* D0 = DoF + (size_t)(b * NT + 0) * 16;
        const float* D1 = DoF + (size_t)(b * NT + 1) * 16;
        float* th = theta + (size_t)b * NT * 12;
        for (int i = 0; i < 12; ++i) th[2 * 12 + i] = 0.f;
        th[2 * 12 + 0] = 1.f; th[2 * 12 + 5] = 1.f; th[2 * 12 + 10] = 1.f;
        for (int i = 0; i < 12; ++i) th[1 * 12 + i] = D1[i];
        for (int r = 0; r < 3; ++r)
            for (int c = 0; c < 4; ++c) {
                float s = (c == 3) ? D0[r * 4 + 3] : 0.f;
                for (int k = 0; k < 3; ++k) s += D0[r * 4 + k] * D1[k * 4 + c];
                th[0 * 12 + r * 4 + c] = s;
            }
    }
}

// ----------------------------------------------------------------------------
// Transpose features (B,T,N,C,FD,FH,FW) fp32 -> [btn][pos][C16] fp32 chlast
// ----------------------------------------------------------------------------
__global__ __launch_bounds__(256) void transpose_feat_f32(
    const float* __restrict__ feat, float* __restrict__ ft) {
    size_t tid = (size_t)blockIdx.x * 256 + threadIdx.x;
    int pos = (int)(tid % FSZ);
    int btn = (int)(tid / FSZ);
    const float* src = feat + (size_t)btn * CAMSZ + pos;
    float v[NC];
#pragma unroll
    for (int c = 0; c < NC; ++c) v[c] = src[(size_t)c * FSZ];
    float4* dst = reinterpret_cast<float4*>(ft + ((size_t)btn * FSZ + pos) * NC);
#pragma unroll
    for (int q = 0; q < 4; ++q)
        dst[q] = make_float4(v[4 * q], v[4 * q + 1], v[4 * q + 2], v[4 * q + 3]);
}

// ----------------------------------------------------------------------------
// Kernel 1: R2's branch-free pipelined body + ONE top-level early-out.
// Prologue tests all 6 cams with multiply-compares (no div/floor), bounds
// widened so borderline voxels fall through to the exact masked main path.
// Threads failing all cams write relu(b_N) and exit.
// ----------------------------------------------------------------------------
template <bool CHLAST>
__global__ __launch_bounds__(256) void sample_mlp1_f32(
    const float* __restrict__ feat,   // original layout (when !CHLAST)
    const float* __restrict__ ft,     // channel-last (when CHLAST)
    const float* __restrict__ P,
    const float* __restrict__ W_N,
    const float* __restrict__ b_N,
    float* __restrict__ h) {
    int tid = blockIdx.x * 256 + threadIdx.x;
    int vid = tid % NVOX;
    int bt = tid / NVOX;
    int gy = vid % GY;
    int r2 = vid / GY;
    int gz = r2 % GZ;
    int gx = r2 / GZ;
    float X = (float)gx - 49.5f;
    float Y = (float)gy - 49.5f;
    float Z = (float)gz - 2.5f;

    // ---- prologue: cheap per-cam validity (widened bounds, no div) ----
    bool anyvalid = false;
#pragma unroll
    for (int n = 0; n < NCAM; ++n) {
        const float* Pp = P + (bt * NCAM + n) * 12;
        float px = Pp[0] * X + Pp[1] * Y + Pp[2] * Z + Pp[3];
        float py = Pp[4] * X + Pp[5] * Y + Pp[6] * Z + Pp[7];
        float pz = Pp[8] * X + Pp[9] * Y + Pp[10] * Z + Pp[11];
        float zc = fmaxf(pz, 1e-5f);
        // ix in [-1, 64): px/zc bounds via multiply (zc > 0); widened 1e-4
        bool ok = (px >= -1.0001f * zc) & (px <= 64.0001f * zc) &
                  (py >= -1.0001f * zc) & (py <= 24.0001f * zc) &
                  (pz >= 1.06666f) & (pz <= 46.8001f);  // iz in [-1, 48)
        anyvalid |= ok;
    }
    if (!anyvalid) {
        // all 8 corner weights are 0 for every cam -> h = relu(bias)
        float4* hp = reinterpret_cast<float4*>(
            h + ((size_t)bt * NVOX + (size_t)vid) * OC);
        const float4* bb = reinterpret_cast<const float4*>(b_N);
#pragma unroll
        for (int q = 0; q < 10; ++q) {
            float4 bv = bb[q];
            hp[q] = make_float4(fmaxf(bv.x, 0.f), fmaxf(bv.y, 0.f),
                                fmaxf(bv.z, 0.f), fmaxf(bv.w, 0.f));
        }
        return;
    }

    // ---- main path: exactly R2's branch-free fully-unrolled pipeline ----
    float acc[OC];
#pragma unroll
    for (int o = 0; o < OC; ++o) acc[o] = b_N[o];

    for (int n = 0; n < NCAM; ++n) {
        const float* Pp = P + (bt * NCAM + n) * 12;
        float px = Pp[0] * X + Pp[1] * Y + Pp[2] * Z + Pp[3];
        float py = Pp[4] * X + Pp[5] * Y + Pp[6] * Z + Pp[7];
        float pz = Pp[8] * X + Pp[9] * Y + Pp[10] * Z + Pp[11];
        float zc = fmaxf(pz, 1e-5f);
        float ix = px / zc;                       // = u (normalization round-trips)
        float iy = py / zc;
        float iz = (pz - 2.0f) * (48.0f / 44.8f); // = dbin
        float x0 = floorf(ix), y0 = floorf(iy), z0 = floorf(iz);
        float wx1 = ix - x0, wy1 = iy - y0, wz1 = iz - z0;
        float wx0 = 1.f - wx1, wy0 = 1.f - wy1, wz0 = 1.f - wz1;

        float w8[8];
        int off8[8];
#pragma unroll
        for (int k = 0; k < 8; ++k) {
            float xf = x0 + (float)(k & 1);
            float yf = y0 + (float)((k >> 1) & 1);
            float zf = z0 + (float)(k >> 2);
            bool valid = (xf >= 0.f) & (xf <= (float)(FW - 1)) &
                         (yf >= 0.f) & (yf <= (float)(FH - 1)) &
                         (zf >= 0.f) & (zf <= (float)(FD - 1));
            int xi = (int)fminf(fmaxf(xf, 0.f), (float)(FW - 1));
            int yi = (int)fminf(fmaxf(yf, 0.f), (float)(FH - 1));
            int zi = (int)fminf(fmaxf(zf, 0.f), (float)(FD - 1));
            float w = ((k & 1) ? wx1 : wx0) * (((k >> 1) & 1) ? wy1 : wy0) *
                      ((k >> 2) ? wz1 : wz0);
            w8[k] = valid ? w : 0.f;
            off8[k] = (zi * FH + yi) * FW + xi;
        }

        float s[NC];
#pragma unroll
        for (int c = 0; c < NC; ++c) s[c] = 0.f;

        if constexpr (CHLAST) {
            const size_t camBase = (size_t)(bt * NCAM + n) * FSZ;
#pragma unroll
            for (int k = 0; k < 8; ++k) {
                float w = w8[k];
                const float4* cp = reinterpret_cast<const float4*>(
                    ft + (camBase + (size_t)off8[k]) * NC);
#pragma unroll
                for (int q = 0; q < 4; ++q) {
                    float4 v = cp[q];
                    s[4 * q + 0] = fmaf(w, v.x, s[4 * q + 0]);
                    s[4 * q + 1] = fmaf(w, v.y, s[4 * q + 1]);
                    s[4 * q + 2] = fmaf(w, v.z, s[4 * q + 2]);
                    s[4 * q + 3] = fmaf(w, v.w, s[4 * q + 3]);
                }
            }
        } else {
            const float* fn = feat + (size_t)bt * BTSZ + (size_t)n * CAMSZ;
#pragma unroll
            for (int c = 0; c < NC; ++c) {
                const float* fc = fn + (size_t)c * FSZ;
                float v = 0.f;
#pragma unroll
                for (int k = 0; k < 8; ++k) v = fmaf(w8[k], fc[off8[k]], v);
                s[c] = v;
            }
        }

        // acc[o] += W_N[o, n*16 + c] * s[c]
#pragma unroll
        for (int o = 0; o < OC; ++o) {
            const float4* w4 =
                reinterpret_cast<const float4*>(W_N + o * (NCAM * NC) + n * NC);
#pragma unroll
            for (int q = 0; q < 4; ++q) {
                float4 w = w4[q];
                acc[o] = fmaf(w.x, s[4 * q + 0], acc[o]);
                acc[o] = fmaf(w.y, s[4 * q + 1], acc[o]);
                acc[o] = fmaf(w.z, s[4 * q + 2], acc[o]);
                acc[o] = fmaf(w.w, s[4 * q + 3], acc[o]);
            }
        }
    }

    float4* hp = reinterpret_cast<float4*>(
        h + ((size_t)bt * NVOX + (size_t)vid) * OC);
#pragma unroll
    for (int q = 0; q < 10; ++q)
        hp[q] = make_float4(fmaxf(acc[4 * q + 0], 0.f), fmaxf(acc[4 * q + 1], 0.f),
                            fmaxf(acc[4 * q + 2], 0.f), fmaxf(acc[4 * q + 3], 0.f));
}

// ----------------------------------------------------------------------------
// Kernel 2 (channel-split): one thread per (b, voxel, t, channel-group-of-8).
// Block = 960 threads = 64 voxels x 3 t x 5 cg; each wave is 64 consecutive
// voxels at uniform (t,cg). Per thread: gather 8 corners x 8 channels
// (2 x float4, 32B-aligned), partial W_T dot-products over its 8 channels,
// LDS-atomic into red[64][41] (stride 41 -> <=2 lanes/bank, free),
// then bias+ReLU+coalesced store. grid = NB*1250 = 2500 blocks, 37.5k waves.
// ----------------------------------------------------------------------------
__global__ __launch_bounds__(960) void warp_mlp2_csplit(
    const float* __restrict__ h,
    const float* __restrict__ theta,
    const float* __restrict__ W_T,
    const float* __restrict__ b_T,
    float* __restrict__ out) {
    __shared__ float red[64][41];
    int tid = threadIdx.x;
    int v = tid & 63;
    int rest = tid >> 6;            // 0..14
    int t = rest % NT;              // wave-uniform
    int cg = rest / NT;             // 0..4, wave-uniform
    int b = blockIdx.x / (NVOX / 64);
    int vb = blockIdx.x % (NVOX / 64);
    int vid = vb * 64 + v;
    int w_ = vid % GY;              // Wp = 100
    int r2 = vid / GY;
    int h_ = r2 % GZ;               // Hp = 8
    int d_ = r2 / GZ;               // Dp = 100

    for (int i = tid; i < 64 * 41; i += 960) (&red[0][0])[i] = 0.f;
    __syncthreads();

    float xg = -1.f + 2.f * (float)w_ / 99.f;
    float yg = -1.f + 2.f * (float)h_ / 7.f;
    float zg = -1.f + 2.f * (float)d_ / 99.f;

    const float* th = theta + (b * NT + t) * 12;
    float g0 = th[0] * xg + th[1] * yg + th[2] * zg + th[3];
    float g1 = th[4] * xg + th[5] * yg + th[6] * zg + th[7];
    float g2 = th[8] * xg + th[9] * yg + th[10] * zg + th[11];
    float ix = (g0 + 1.f) * 0.5f * 99.f;
    float iy = (g1 + 1.f) * 0.5f * 7.f;
    float iz = (g2 + 1.f) * 0.5f * 99.f;
    float x0 = floorf(ix), y0 = floorf(iy), z0 = floorf(iz);
    float wx1 = ix - x0, wy1 = iy - y0, wz1 = iz - z0;
    float wx0 = 1.f - wx1, wy0 = 1.f - wy1, wz0 = 1.f - wz1;

    float w8[8];
    int off8[8];
#pragma unroll
    for (int k = 0; k < 8; ++k) {
        float xf = x0 + (float)(k & 1);
        float yf = y0 + (float)((k >> 1) & 1);
        float zf = z0 + (float)(k >> 2);
        bool valid = (xf >= 0.f) & (xf <= 99.f) &
                     (yf >= 0.f) & (yf <= 7.f) &
                     (zf >= 0.f) & (zf <= 99.f);
        int xi = (int)fminf(fmaxf(xf, 0.f), 99.f);
        int yi = (int)fminf(fmaxf(yf, 0.f), 7.f);
        int zi = (int)fminf(fmaxf(zf, 0.f), 99.f);
        float w = ((k & 1) ? wx1 : wx0) * (((k >> 1) & 1) ? wy1 : wy0) *
                  ((k >> 2) ? wz1 : wz0);
        w8[k] = valid ? w : 0.f;
        off8[k] = (zi * GZ + yi) * GY + xi;
    }

    // gather: 8 corners x 8 channels (this thread's cg slice)
    const float* hb = h + (size_t)(b * NT + t) * NVOX * OC + cg * 8;
    float sv[8];
#pragma unroll
    for (int j = 0; j < 8; ++j) sv[j] = 0.f;
#pragma unroll
    for (int k = 0; k < 8; ++k) {
        float w = w8[k];
        const float4* cp =
            reinterpret_cast<const float4*>(hb + (size_t)off8[k] * OC);
        float4 a = cp[0], c = cp[1];
        sv[0] = fmaf(w, a.x, sv[0]); sv[1] = fmaf(w, a.y, sv[1]);
        sv[2] = fmaf(w, a.z, sv[2]); sv[3] = fmaf(w, a.w, sv[3]);
        sv[4] = fmaf(w, c.x, sv[4]); sv[5] = fmaf(w, c.y, sv[5]);
        sv[6] = fmaf(w, c.z, sv[6]); sv[7] = fmaf(w, c.w, sv[7]);
    }

    // partial[o] = sum_{j<8} W_T[o, t*40 + cg*8 + j] * sv[j]
    const float* wt = W_T + t * OC + cg * 8;   // row o: wt + o*120 (32B-aligned)
#pragma unroll
    for (int o = 0; o < OC; o += 4) {
        const float4* r0 = reinterpret_cast<const float4*>(wt + (o + 0) * (NT * OC));
        const float4* r1 = reinterpret_cast<const float4*>(wt + (o + 1) * (NT * OC));
        const float4* r2p = reinterpret_cast<const float4*>(wt + (o + 2) * (NT * OC));
        const float4* r3 = reinterpret_cast<const float4*>(wt + (o + 3) * (NT * OC));
        float4 a0 = r0[0], c0 = r0[1];
        float4 a1 = r1[0], c1 = r1[1];
        float4 a2 = r2p[0], c2 = r2p[1];
        float4 a3 = r3[0], c3 = r3[1];
        float p0 = 0.f, p1 = 0.f, p2 = 0.f, p3 = 0.f;
        p0 = fmaf(a0.x, sv[0], p0); p0 = fmaf(a0.y, sv[1], p0);
        p0 = fmaf(a0.z, sv[2], p0); p0 = fmaf(a0.w, sv[3], p0);
        p0 = fmaf(c0.x, sv[4], p0); p0 = fmaf(c0.y, sv[5], p0);
        p0 = fmaf(c0.z, sv[6], p0); p0 = fmaf(c0.w, sv[7], p0);
        p1 = fmaf(a1.x, sv[0], p1); p1 = fmaf(a1.y, sv[1], p1);
        p1 = fmaf(a1.z, sv[2], p1); p1 = fmaf(a1.w, sv[3], p1);
        p1 = fmaf(c1.x, sv[4], p1); p1 = fmaf(c1.y, sv[5], p1);
        p1 = fmaf(c1.z, sv[6], p1); p1 = fmaf(c1.w, sv[7], p1);
        p2 = fmaf(a2.x, sv[0], p2); p2 = fmaf(a2.y, sv[1], p2);
        p2 = fmaf(a2.z, sv[2], p2); p2 = fmaf(a2.w, sv[3], p2);
        p2 = fmaf(c2.x, sv[4], p2); p2 = fmaf(c2.y, sv[5], p2);
        p2 = fmaf(c2.z, sv[6], p2); p2 = fmaf(c2.w, sv[7], p2);
        p3 = fmaf(a3.x, sv[0], p3); p3 = fmaf(a3.y, sv[1], p3);
        p3 = fmaf(a3.z, sv[2], p3); p3 = fmaf(a3.w, sv[3], p3);
        p3 = fmaf(c3.x, sv[4], p3); p3 = fmaf(c3.y, sv[5], p3);
        p3 = fmaf(c3.z, sv[6], p3); p3 = fmaf(c3.w, sv[7], p3);
        atomicAdd(&red[v][o + 0], p0);
        atomicAdd(&red[v][o + 1], p1);
        atomicAdd(&red[v][o + 2], p2);
        atomicAdd(&red[v][o + 3], p3);
    }
    __syncthreads();

    // write out: 64 voxels x 40 outputs; coalesced rows of 64
    for (int idx = tid; idx < 64 * OC; idx += 960) {
        int o = idx >> 6;
        int vv = idx & 63;
        float val = red[vv][o] + b_T[o];
        out[((size_t)b * OC + o) * NVOX + (size_t)vb * 64 + vv] = fmaxf(val, 0.f);
    }
}

extern "C" void kernel_launch(void* const* d_in, const int* in_sizes, int n_in,
                              void* d_out, int out_size, void* d_ws, size_t ws_size,
                              hipStream_t stream) {
    const float* frustum = (const float*)d_in[0];
    const float* RT      = (const float*)d_in[1];
    const float* intrins = (const float*)d_in[2];
    const float* DoF     = (const float*)d_in[3];
    const float* W_N     = (const float*)d_in[4];
    const float* b_N     = (const float*)d_in[5];
    const float* W_T     = (const float*)d_in[6];
    const float* b_T     = (const float*)d_in[7];
    float* out = (float*)d_out;

    const size_t ft_f32 = FT_ELEMS * sizeof(float);   // ~170 MB
    const size_t h_f32  = HSZ * sizeof(float);        // ~77 MB
    const size_t small  = 4096;

    char* base = (char*)d_ws;
    const int tr_blocks = (NB * NT * NCAM * FSZ) / 256;  // 10368
    const int n1_blocks = (NB * NT * NVOX) / 256;        // 1875
    const int n2_blocks = NB * (NVOX / 64);              // 2500

    if (ws_size >= ft_f32 + h_f32 + small) {
        // fast path: fp32 channel-last features
        size_t ft_al = (ft_f32 + 255) & ~(size_t)255;
        float* ft_buf = (float*)base;
        float* h_buf = (float*)(base + ft_al);
        float* P_buf = (float*)(base + ft_al + ((h_f32 + 255) & ~(size_t)255));
        float* th_buf = P_buf + NB * NT * NCAM * 12;

        setup_kernel<<<1, 128, 0, stream>>>(RT, intrins, DoF, P_buf, th_buf);
        transpose_feat_f32<<<tr_blocks, 256, 0, stream>>>(frustum, ft_buf);
        sample_mlp1_f32<true><<<n1_blocks, 256, 0, stream>>>(
            nullptr, ft_buf, P_buf, W_N, b_N, h_buf);
        warp_mlp2_csplit<<<n2_blocks, 960, 0, stream>>>(
            h_buf, th_buf, W_T, b_T, out);
    } else {
        // fallback: no feature transpose (original layout gathers), fp32 h
        float* h_buf = (float*)base;
        float* P_buf = (float*)(base + ((h_f32 + 255) & ~(size_t)255));
        float* th_buf = P_buf + NB * NT * NCAM * 12;

        setup_kernel<<<1, 128, 0, stream>>>(RT, intrins, DoF, P_buf, th_buf);
        sample_mlp1_f32<false><<<n1_blocks, 256, 0, stream>>>(
            frustum, nullptr, P_buf, W_N, b_N, h_buf);
        warp_mlp2_csplit<<<n2_blocks, 960, 0, stream>>>(
            h_buf, th_buf, W_T, b_T, out);
    }
}

// Round 6
// 551.461 us; speedup vs baseline: 1.6908x; 1.6908x over previous
//
#include <hip/hip_runtime.h>

// ---- problem constants (from reference) ----
#define NB 2
#define NT 3
#define NCAM 6
#define NC 16
#define FD 48
#define FH 24
#define FW 64
#define GX 100
#define GY 100
#define GZ 8
#define OC 40
#define NVOX (GX * GY * GZ)          // 80000
#define FSZ (FD * FH * FW)           // 73728 voxels per channel volume
#define CAMSZ (NC * FSZ)             // per-camera feature volume (orig layout)
#define BTSZ (NCAM * CAMSZ)          // per-(b,t) feature block (orig layout)
#define HSZ ((size_t)NB * NT * OC * NVOX)             // 19,200,000 elems
#define FT_ELEMS ((size_t)NB * NT * NCAM * FSZ * NC)  // 42,467,328 elems

// ----------------------------------------------------------------------------
// Setup: P[b,t,n] = intrins[b] @ RT[b,t,n][:3,:]  (3x4)
//        theta[b,t] cumulative affine (3x4): t=2 -> I, t=1 -> M4[b,1],
//        t=0 -> M4[b,0] @ M4[b,1]
// ----------------------------------------------------------------------------
__global__ void setup_kernel(const float* __restrict__ RT,
                             const float* __restrict__ intrins,
                             const float* __restrict__ DoF,
                             float* __restrict__ P,
                             float* __restrict__ theta) {
    int tid = threadIdx.x;
    if (tid < NB * NT * NCAM) {
        int bt = tid / NCAM;
        int b = bt / NT;
        const float* I3 = intrins + b * 9;
        const float* R = RT + (size_t)tid * 16;
        float* Pp = P + tid * 12;
        for (int r = 0; r < 3; ++r)
            for (int c = 0; c < 4; ++c) {
                float s = 0.f;
                for (int k = 0; k < 3; ++k) s += I3[r * 3 + k] * R[k * 4 + c];
                Pp[r * 4 + c] = s;
            }
    }
    if (tid >= 64 && tid < 64 + NB) {
        int b = tid - 64;
        const float* D0 = DoF + (size_t)(b * NT + 0) * 16;
        const float* D1 = DoF + (size_t)(b * NT + 1) * 16;
        float* th = theta + (size_t)b * NT * 12;
        for (int i = 0; i < 12; ++i) th[2 * 12 + i] = 0.f;
        th[2 * 12 + 0] = 1.f; th[2 * 12 + 5] = 1.f; th[2 * 12 + 10] = 1.f;
        for (int i = 0; i < 12; ++i) th[1 * 12 + i] = D1[i];
        for (int r = 0; r < 3; ++r)
            for (int c = 0; c < 4; ++c) {
                float s = (c == 3) ? D0[r * 4 + 3] : 0.f;
                for (int k = 0; k < 3; ++k) s += D0[r * 4 + k] * D1[k * 4 + c];
                th[0 * 12 + r * 4 + c] = s;
            }
    }
}

// ----------------------------------------------------------------------------
// Transpose features (B,T,N,C,FD,FH,FW) fp32 -> [btn][pos][C16] fp32 chlast
// ----------------------------------------------------------------------------
__global__ __launch_bounds__(256) void transpose_feat_f32(
    const float* __restrict__ feat, float* __restrict__ ft) {
    size_t tid = (size_t)blockIdx.x * 256 + threadIdx.x;
    int pos = (int)(tid % FSZ);
    int btn = (int)(tid / FSZ);
    const float* src = feat + (size_t)btn * CAMSZ + pos;
    float v[NC];
#pragma unroll
    for (int c = 0; c < NC; ++c) v[c] = src[(size_t)c * FSZ];
    float4* dst = reinterpret_cast<float4*>(ft + ((size_t)btn * FSZ + pos) * NC);
#pragma unroll
    for (int q = 0; q < 4; ++q)
        dst[q] = make_float4(v[4 * q], v[4 * q + 1], v[4 * q + 2], v[4 * q + 3]);
}

// ----------------------------------------------------------------------------
// Kernel 1: EXACT R2 branch-free body (no cull, no early-out — per-thread MLP
// from 192 independent loads is what hides latency; see R4/R5 post-mortems).
// Only change vs R2: h stored CHANNEL-FIRST [bt][o][vid] via 40 coalesced
// scalar stores (enables coalesced gathers in kernel 2).
// ----------------------------------------------------------------------------
template <bool CHLAST>
__global__ __launch_bounds__(256) void sample_mlp1_f32(
    const float* __restrict__ feat,   // original layout (when !CHLAST)
    const float* __restrict__ ft,     // channel-last (when CHLAST)
    const float* __restrict__ P,
    const float* __restrict__ W_N,
    const float* __restrict__ b_N,
    float* __restrict__ h) {
    int tid = blockIdx.x * 256 + threadIdx.x;
    int vid = tid % NVOX;
    int bt = tid / NVOX;
    int gy = vid % GY;
    int r2 = vid / GY;
    int gz = r2 % GZ;
    int gx = r2 / GZ;
    float X = (float)gx - 49.5f;
    float Y = (float)gy - 49.5f;
    float Z = (float)gz - 2.5f;

    float acc[OC];
#pragma unroll
    for (int o = 0; o < OC; ++o) acc[o] = b_N[o];

    for (int n = 0; n < NCAM; ++n) {
        const float* Pp = P + (bt * NCAM + n) * 12;
        float px = Pp[0] * X + Pp[1] * Y + Pp[2] * Z + Pp[3];
        float py = Pp[4] * X + Pp[5] * Y + Pp[6] * Z + Pp[7];
        float pz = Pp[8] * X + Pp[9] * Y + Pp[10] * Z + Pp[11];
        float zc = fmaxf(pz, 1e-5f);
        float ix = px / zc;                       // = u (normalization round-trips)
        float iy = py / zc;
        float iz = (pz - 2.0f) * (48.0f / 44.8f); // = dbin
        float x0 = floorf(ix), y0 = floorf(iy), z0 = floorf(iz);
        float wx1 = ix - x0, wy1 = iy - y0, wz1 = iz - z0;
        float wx0 = 1.f - wx1, wy0 = 1.f - wy1, wz0 = 1.f - wz1;

        float w8[8];
        int off8[8];
#pragma unroll
        for (int k = 0; k < 8; ++k) {
            float xf = x0 + (float)(k & 1);
            float yf = y0 + (float)((k >> 1) & 1);
            float zf = z0 + (float)(k >> 2);
            bool valid = (xf >= 0.f) & (xf <= (float)(FW - 1)) &
                         (yf >= 0.f) & (yf <= (float)(FH - 1)) &
                         (zf >= 0.f) & (zf <= (float)(FD - 1));
            int xi = (int)fminf(fmaxf(xf, 0.f), (float)(FW - 1));
            int yi = (int)fminf(fmaxf(yf, 0.f), (float)(FH - 1));
            int zi = (int)fminf(fmaxf(zf, 0.f), (float)(FD - 1));
            float w = ((k & 1) ? wx1 : wx0) * (((k >> 1) & 1) ? wy1 : wy0) *
                      ((k >> 2) ? wz1 : wz0);
            w8[k] = valid ? w : 0.f;
            off8[k] = (zi * FH + yi) * FW + xi;
        }

        float s[NC];
#pragma unroll
        for (int c = 0; c < NC; ++c) s[c] = 0.f;

        if constexpr (CHLAST) {
            const size_t camBase = (size_t)(bt * NCAM + n) * FSZ;
#pragma unroll
            for (int k = 0; k < 8; ++k) {
                float w = w8[k];
                const float4* cp = reinterpret_cast<const float4*>(
                    ft + (camBase + (size_t)off8[k]) * NC);
#pragma unroll
                for (int q = 0; q < 4; ++q) {
                    float4 v = cp[q];
                    s[4 * q + 0] = fmaf(w, v.x, s[4 * q + 0]);
                    s[4 * q + 1] = fmaf(w, v.y, s[4 * q + 1]);
                    s[4 * q + 2] = fmaf(w, v.z, s[4 * q + 2]);
                    s[4 * q + 3] = fmaf(w, v.w, s[4 * q + 3]);
                }
            }
        } else {
            const float* fn = feat + (size_t)bt * BTSZ + (size_t)n * CAMSZ;
#pragma unroll
            for (int c = 0; c < NC; ++c) {
                const float* fc = fn + (size_t)c * FSZ;
                float v = 0.f;
#pragma unroll
                for (int k = 0; k < 8; ++k) v = fmaf(w8[k], fc[off8[k]], v);
                s[c] = v;
            }
        }

        // acc[o] += W_N[o, n*16 + c] * s[c]
#pragma unroll
        for (int o = 0; o < OC; ++o) {
            const float4* w4 =
                reinterpret_cast<const float4*>(W_N + o * (NCAM * NC) + n * NC);
#pragma unroll
            for (int q = 0; q < 4; ++q) {
                float4 w = w4[q];
                acc[o] = fmaf(w.x, s[4 * q + 0], acc[o]);
                acc[o] = fmaf(w.y, s[4 * q + 1], acc[o]);
                acc[o] = fmaf(w.z, s[4 * q + 2], acc[o]);
                acc[o] = fmaf(w.w, s[4 * q + 3], acc[o]);
            }
        }
    }

    // CHANNEL-FIRST store: h[bt][o][vid], 40 coalesced scalar stores
    float* hp = h + (size_t)bt * OC * NVOX + vid;
#pragma unroll
    for (int o = 0; o < OC; ++o) hp[(size_t)o * NVOX] = fmaxf(acc[o], 0.f);
}

// ----------------------------------------------------------------------------
// Kernel 2 (t-split, channel-first gathers): one thread per (b, voxel, t).
// Block = 192 threads = 64 consecutive voxels x 3 waves (wave w <-> t=w).
// h is [bt][o][vid]: corner load h_t[o*NVOX + off8[k]] has lanes = consecutive
// voxels -> COALESCED 4B/lane (~1-2 cache lines per wave-instr, vs 64 lines
// for the channel-last 16B gathers that bound R4/R5's k2).
// 320 independent loads/thread; LDS red[64][41] atomic reduce as in R4.
// grid = NB * NVOX/64 = 2500 blocks -> 7500 waves.
// ----------------------------------------------------------------------------
__global__ __launch_bounds__(192) void warp_mlp2_tsplit_cf(
    const float* __restrict__ h,
    const float* __restrict__ theta,
    const float* __restrict__ W_T,
    const float* __restrict__ b_T,
    float* __restrict__ out) {
    __shared__ float red[64][41];   // stride 41 -> <=2 lanes/bank (free)
    int tid = threadIdx.x;
    int t = tid >> 6;               // wave index = temporal index
    int v = tid & 63;
    int b = blockIdx.x / (NVOX / 64);
    int vb = blockIdx.x % (NVOX / 64);
    int vid = vb * 64 + v;
    int w_ = vid % GY;              // Wp = 100
    int r2 = vid / GY;
    int h_ = r2 % GZ;               // Hp = 8
    int d_ = r2 / GZ;               // Dp = 100

    for (int i = tid; i < 64 * 41; i += 192) (&red[0][0])[i] = 0.f;
    __syncthreads();

    float xg = -1.f + 2.f * (float)w_ / 99.f;
    float yg = -1.f + 2.f * (float)h_ / 7.f;
    float zg = -1.f + 2.f * (float)d_ / 99.f;

    const float* th = theta + (b * NT + t) * 12;
    float g0 = th[0] * xg + th[1] * yg + th[2] * zg + th[3];
    float g1 = th[4] * xg + th[5] * yg + th[6] * zg + th[7];
    float g2 = th[8] * xg + th[9] * yg + th[10] * zg + th[11];
    float ix = (g0 + 1.f) * 0.5f * 99.f;
    float iy = (g1 + 1.f) * 0.5f * 7.f;
    float iz = (g2 + 1.f) * 0.5f * 99.f;
    float x0 = floorf(ix), y0 = floorf(iy), z0 = floorf(iz);
    float wx1 = ix - x0, wy1 = iy - y0, wz1 = iz - z0;
    float wx0 = 1.f - wx1, wy0 = 1.f - wy1, wz0 = 1.f - wz1;

    float w8[8];
    int off8[8];
#pragma unroll
    for (int k = 0; k < 8; ++k) {
        float xf = x0 + (float)(k & 1);
        float yf = y0 + (float)((k >> 1) & 1);
        float zf = z0 + (float)(k >> 2);
        bool valid = (xf >= 0.f) & (xf <= 99.f) &
                     (yf >= 0.f) & (yf <= 7.f) &
                     (zf >= 0.f) & (zf <= 99.f);
        int xi = (int)fminf(fmaxf(xf, 0.f), 99.f);
        int yi = (int)fminf(fmaxf(yf, 0.f), 7.f);
        int zi = (int)fminf(fmaxf(zf, 0.f), 99.f);
        float w = ((k & 1) ? wx1 : wx0) * (((k >> 1) & 1) ? wy1 : wy0) *
                  ((k >> 2) ? wz1 : wz0);
        w8[k] = valid ? w : 0.f;
        off8[k] = (zi * GZ + yi) * GY + xi;
    }

    // coalesced gathers: sval[o] = sum_k w8[k] * h_t[o*NVOX + off8[k]]
    const float* ht = h + (size_t)(b * NT + t) * OC * NVOX;
    float sval[OC];
#pragma unroll
    for (int o = 0; o < OC; ++o) {
        const float* ho = ht + (size_t)o * NVOX;
        float v0 = 0.f;
#pragma unroll
        for (int k = 0; k < 8; ++k) v0 = fmaf(w8[k], ho[off8[k]], v0);
        sval[o] = v0;
    }

    // partial[o] = sum_o2 W_T[o, t*40 + o2] * sval[o2]; 4 outputs at a time
#pragma unroll
    for (int o = 0; o < OC; o += 4) {
        float p0 = 0.f, p1 = 0.f, p2 = 0.f, p3 = 0.f;
        const float4* w0 = reinterpret_cast<const float4*>(
            W_T + (o + 0) * (NT * OC) + t * OC);
        const float4* w1 = reinterpret_cast<const float4*>(
            W_T + (o + 1) * (NT * OC) + t * OC);
        const float4* w2 = reinterpret_cast<const float4*>(
            W_T + (o + 2) * (NT * OC) + t * OC);
        const float4* w3 = reinterpret_cast<const float4*>(
            W_T + (o + 3) * (NT * OC) + t * OC);
#pragma unroll
        for (int q = 0; q < 10; ++q) {
            float4 a0 = w0[q], a1 = w1[q], a2 = w2[q], a3 = w3[q];
            float s0 = sval[4 * q + 0], s1 = sval[4 * q + 1];
            float s2 = sval[4 * q + 2], s3 = sval[4 * q + 3];
            p0 = fmaf(a0.x, s0, p0); p0 = fmaf(a0.y, s1, p0);
            p0 = fmaf(a0.z, s2, p0); p0 = fmaf(a0.w, s3, p0);
            p1 = fmaf(a1.x, s0, p1); p1 = fmaf(a1.y, s1, p1);
            p1 = fmaf(a1.z, s2, p1); p1 = fmaf(a1.w, s3, p1);
            p2 = fmaf(a2.x, s0, p2); p2 = fmaf(a2.y, s1, p2);
            p2 = fmaf(a2.z, s2, p2); p2 = fmaf(a2.w, s3, p2);
            p3 = fmaf(a3.x, s0, p3); p3 = fmaf(a3.y, s1, p3);
            p3 = fmaf(a3.z, s2, p3); p3 = fmaf(a3.w, s3, p3);
        }
        atomicAdd(&red[v][o + 0], p0);
        atomicAdd(&red[v][o + 1], p1);
        atomicAdd(&red[v][o + 2], p2);
        atomicAdd(&red[v][o + 3], p3);
    }
    __syncthreads();

    // write out: 64 voxels x 40 outputs; coalesced rows of 64
    for (int idx = tid; idx < 64 * OC; idx += 192) {
        int o = idx >> 6;
        int vv = idx & 63;
        float val = red[vv][o] + b_T[o];
        out[((size_t)b * OC + o) * NVOX + (size_t)vb * 64 + vv] = fmaxf(val, 0.f);
    }
}

extern "C" void kernel_launch(void* const* d_in, const int* in_sizes, int n_in,
                              void* d_out, int out_size, void* d_ws, size_t ws_size,
                              hipStream_t stream) {
    const float* frustum = (const float*)d_in[0];
    const float* RT      = (const float*)d_in[1];
    const float* intrins = (const float*)d_in[2];
    const float* DoF     = (const float*)d_in[3];
    const float* W_N     = (const float*)d_in[4];
    const float* b_N     = (const float*)d_in[5];
    const float* W_T     = (const float*)d_in[6];
    const float* b_T     = (const float*)d_in[7];
    float* out = (float*)d_out;

    const size_t ft_f32 = FT_ELEMS * sizeof(float);   // ~170 MB
    const size_t h_f32  = HSZ * sizeof(float);        // ~77 MB
    const size_t small  = 4096;

    char* base = (char*)d_ws;
    const int tr_blocks = (NB * NT * NCAM * FSZ) / 256;  // 10368
    const int n1_blocks = (NB * NT * NVOX) / 256;        // 1875
    const int n2_blocks = NB * (NVOX / 64);              // 2500

    if (ws_size >= ft_f32 + h_f32 + small) {
        // fast path: fp32 channel-last features
        size_t ft_al = (ft_f32 + 255) & ~(size_t)255;
        float* ft_buf = (float*)base;
        float* h_buf = (float*)(base + ft_al);
        float* P_buf = (float*)(base + ft_al + ((h_f32 + 255) & ~(size_t)255));
        float* th_buf = P_buf + NB * NT * NCAM * 12;

        setup_kernel<<<1, 128, 0, stream>>>(RT, intrins, DoF, P_buf, th_buf);
        transpose_feat_f32<<<tr_blocks, 256, 0, stream>>>(frustum, ft_buf);
        sample_mlp1_f32<true><<<n1_blocks, 256, 0, stream>>>(
            nullptr, ft_buf, P_buf, W_N, b_N, h_buf);
        warp_mlp2_tsplit_cf<<<n2_blocks, 192, 0, stream>>>(
            h_buf, th_buf, W_T, b_T, out);
    } else {
        // fallback: no feature transpose (original layout gathers)
        float* h_buf = (float*)base;
        float* P_buf = (float*)(base + ((h_f32 + 255) & ~(size_t)255));
        float* th_buf = P_buf + NB * NT * NCAM * 12;

        setup_kernel<<<1, 128, 0, stream>>>(RT, intrins, DoF, P_buf, th_buf);
        sample_mlp1_f32<false><<<n1_blocks, 256, 0, stream>>>(
            frustum, nullptr, P_buf, W_N, b_N, h_buf);
        warp_mlp2_tsplit_cf<<<n2_blocks, 192, 0, stream>>>(
            h_buf, th_buf, W_T, b_T, out);
    }
}

// Round 7
// 529.371 us; speedup vs baseline: 1.7613x; 1.0417x over previous
//
#include <hip/hip_runtime.h>

// ---- problem constants (from reference) ----
#define NB 2
#define NT 3
#define NCAM 6
#define NC 16
#define FD 48
#define FH 24
#define FW 64
#define GX 100
#define GY 100
#define GZ 8
#define OC 40
#define NVOX (GX * GY * GZ)          // 80000
#define FSZ (FD * FH * FW)           // 73728 voxels per channel volume
#define CAMSZ (NC * FSZ)             // per-camera feature volume (orig layout)
#define BTSZ (NCAM * CAMSZ)          // per-(b,t) feature block (orig layout)
#define HSZ ((size_t)NB * NT * OC * NVOX)             // 19,200,000 elems
#define FT_ELEMS ((size_t)NB * NT * NCAM * FSZ * NC)  // 42,467,328 elems

// ----------------------------------------------------------------------------
// Setup: P[b,t,n] = intrins[b] @ RT[b,t,n][:3,:]  (3x4)
//        theta[b,t] cumulative affine (3x4): t=2 -> I, t=1 -> M4[b,1],
//        t=0 -> M4[b,0] @ M4[b,1]
// ----------------------------------------------------------------------------
__global__ void setup_kernel(const float* __restrict__ RT,
                             const float* __restrict__ intrins,
                             const float* __restrict__ DoF,
                             float* __restrict__ P,
                             float* __restrict__ theta) {
    int tid = threadIdx.x;
    if (tid < NB * NT * NCAM) {
        int bt = tid / NCAM;
        int b = bt / NT;
        const float* I3 = intrins + b * 9;
        const float* R = RT + (size_t)tid * 16;
        float* Pp = P + tid * 12;
        for (int r = 0; r < 3; ++r)
            for (int c = 0; c < 4; ++c) {
                float s = 0.f;
                for (int k = 0; k < 3; ++k) s += I3[r * 3 + k] * R[k * 4 + c];
                Pp[r * 4 + c] = s;
            }
    }
    if (tid >= 64 && tid < 64 + NB) {
        int b = tid - 64;
        const float* D0 = DoF + (size_t)(b * NT + 0) * 16;
        const float* D1 = DoF + (size_t)(b * NT + 1) * 16;
        float* th = theta + (size_t)b * NT * 12;
        for (int i = 0; i < 12; ++i) th[2 * 12 + i] = 0.f;
        th[2 * 12 + 0] = 1.f; th[2 * 12 + 5] = 1.f; th[2 * 12 + 10] = 1.f;
        for (int i = 0; i < 12; ++i) th[1 * 12 + i] = D1[i];
        for (int r = 0; r < 3; ++r)
            for (int c = 0; c < 4; ++c) {
                float s = (c == 3) ? D0[r * 4 + 3] : 0.f;
                for (int k = 0; k < 3; ++k) s += D0[r * 4 + k] * D1[k * 4 + c];
                th[0 * 12 + r * 4 + c] = s;
            }
    }
}

// ----------------------------------------------------------------------------
// Transpose features (B,T,N,C,FD,FH,FW) fp32 -> [btn][pos][C16] fp32 chlast
// COALESCED-WRITE version: 4 threads per pos, each owning one float4 (4
// channels). lane = pos*4+q  =>  store addr = lane*16B (contiguous 1KB/wave).
// Old version stored 16B at 64B stride per lane = 64 lines/instr (the hidden
// ~230us elephant per R4/R5/R6 cross-round algebra).
// Reads: 4 per thread; per instr, lanes form 4 contiguous 64B segments.
// ----------------------------------------------------------------------------
__global__ __launch_bounds__(256) void transpose_feat_f32_v2(
    const float* __restrict__ feat, float* __restrict__ ft) {
    size_t tid = (size_t)blockIdx.x * 256 + threadIdx.x;
    int q = (int)(tid & 3);              // channel quad 0..3
    size_t rec = tid >> 2;               // btn*FSZ + pos
    int pos = (int)(rec % FSZ);
    int btn = (int)(rec / FSZ);
    const float* src = feat + (size_t)btn * CAMSZ + (size_t)(q * 4) * FSZ + pos;
    float v0 = src[0 * FSZ];
    float v1 = src[1 * FSZ];
    float v2 = src[2 * FSZ];
    float v3 = src[3 * FSZ];
    float4* dst = reinterpret_cast<float4*>(ft + rec * NC + q * 4);
    dst[0] = make_float4(v0, v1, v2, v3);
}

// ----------------------------------------------------------------------------
// Kernel 1: EXACT R2 branch-free body (no cull, no early-out — per-thread MLP
// from 192 independent loads is what hides latency; see R4/R5 post-mortems).
// h stored CHANNEL-FIRST [bt][o][vid] via 40 coalesced scalar stores
// (enables coalesced gathers in kernel 2).
// ----------------------------------------------------------------------------
template <bool CHLAST>
__global__ __launch_bounds__(256) void sample_mlp1_f32(
    const float* __restrict__ feat,   // original layout (when !CHLAST)
    const float* __restrict__ ft,     // channel-last (when CHLAST)
    const float* __restrict__ P,
    const float* __restrict__ W_N,
    const float* __restrict__ b_N,
    float* __restrict__ h) {
    int tid = blockIdx.x * 256 + threadIdx.x;
    int vid = tid % NVOX;
    int bt = tid / NVOX;
    int gy = vid % GY;
    int r2 = vid / GY;
    int gz = r2 % GZ;
    int gx = r2 / GZ;
    float X = (float)gx - 49.5f;
    float Y = (float)gy - 49.5f;
    float Z = (float)gz - 2.5f;

    float acc[OC];
#pragma unroll
    for (int o = 0; o < OC; ++o) acc[o] = b_N[o];

    for (int n = 0; n < NCAM; ++n) {
        const float* Pp = P + (bt * NCAM + n) * 12;
        float px = Pp[0] * X + Pp[1] * Y + Pp[2] * Z + Pp[3];
        float py = Pp[4] * X + Pp[5] * Y + Pp[6] * Z + Pp[7];
        float pz = Pp[8] * X + Pp[9] * Y + Pp[10] * Z + Pp[11];
        float zc = fmaxf(pz, 1e-5f);
        float ix = px / zc;                       // = u (normalization round-trips)
        float iy = py / zc;
        float iz = (pz - 2.0f) * (48.0f / 44.8f); // = dbin
        float x0 = floorf(ix), y0 = floorf(iy), z0 = floorf(iz);
        float wx1 = ix - x0, wy1 = iy - y0, wz1 = iz - z0;
        float wx0 = 1.f - wx1, wy0 = 1.f - wy1, wz0 = 1.f - wz1;

        float w8[8];
        int off8[8];
#pragma unroll
        for (int k = 0; k < 8; ++k) {
            float xf = x0 + (float)(k & 1);
            float yf = y0 + (float)((k >> 1) & 1);
            float zf = z0 + (float)(k >> 2);
            bool valid = (xf >= 0.f) & (xf <= (float)(FW - 1)) &
                         (yf >= 0.f) & (yf <= (float)(FH - 1)) &
                         (zf >= 0.f) & (zf <= (float)(FD - 1));
            int xi = (int)fminf(fmaxf(xf, 0.f), (float)(FW - 1));
            int yi = (int)fminf(fmaxf(yf, 0.f), (float)(FH - 1));
            int zi = (int)fminf(fmaxf(zf, 0.f), (float)(FD - 1));
            float w = ((k & 1) ? wx1 : wx0) * (((k >> 1) & 1) ? wy1 : wy0) *
                      ((k >> 2) ? wz1 : wz0);
            w8[k] = valid ? w : 0.f;
            off8[k] = (zi * FH + yi) * FW + xi;
        }

        float s[NC];
#pragma unroll
        for (int c = 0; c < NC; ++c) s[c] = 0.f;

        if constexpr (CHLAST) {
            const size_t camBase = (size_t)(bt * NCAM + n) * FSZ;
#pragma unroll
            for (int k = 0; k < 8; ++k) {
                float w = w8[k];
                const float4* cp = reinterpret_cast<const float4*>(
                    ft + (camBase + (size_t)off8[k]) * NC);
#pragma unroll
                for (int q = 0; q < 4; ++q) {
                    float4 v = cp[q];
                    s[4 * q + 0] = fmaf(w, v.x, s[4 * q + 0]);
                    s[4 * q + 1] = fmaf(w, v.y, s[4 * q + 1]);
                    s[4 * q + 2] = fmaf(w, v.z, s[4 * q + 2]);
                    s[4 * q + 3] = fmaf(w, v.w, s[4 * q + 3]);
                }
            }
        } else {
            const float* fn = feat + (size_t)bt * BTSZ + (size_t)n * CAMSZ;
#pragma unroll
            for (int c = 0; c < NC; ++c) {
                const float* fc = fn + (size_t)c * FSZ;
                float v = 0.f;
#pragma unroll
                for (int k = 0; k < 8; ++k) v = fmaf(w8[k], fc[off8[k]], v);
                s[c] = v;
            }
        }

        // acc[o] += W_N[o, n*16 + c] * s[c]
#pragma unroll
        for (int o = 0; o < OC; ++o) {
            const float4* w4 =
                reinterpret_cast<const float4*>(W_N + o * (NCAM * NC) + n * NC);
#pragma unroll
            for (int q = 0; q < 4; ++q) {
                float4 w = w4[q];
                acc[o] = fmaf(w.x, s[4 * q + 0], acc[o]);
                acc[o] = fmaf(w.y, s[4 * q + 1], acc[o]);
                acc[o] = fmaf(w.z, s[4 * q + 2], acc[o]);
                acc[o] = fmaf(w.w, s[4 * q + 3], acc[o]);
            }
        }
    }

    // CHANNEL-FIRST store: h[bt][o][vid], 40 coalesced scalar stores
    float* hp = h + (size_t)bt * OC * NVOX + vid;
#pragma unroll
    for (int o = 0; o < OC; ++o) hp[(size_t)o * NVOX] = fmaxf(acc[o], 0.f);
}

// ----------------------------------------------------------------------------
// Kernel 2 (t-split, channel-first gathers): one thread per (b, voxel, t).
// Block = 192 threads = 64 consecutive voxels x 3 waves (wave w <-> t=w).
// h is [bt][o][vid]: corner load h_t[o*NVOX + off8[k]] has lanes = consecutive
// voxels -> COALESCED 4B/lane. t=2 FAST PATH: theta[b][2] == I exactly (cum
// starts at eye in the reference) and the grid normalization round-trips
// ((xg+1)*0.5*99 == w_ in fp32), so the trilinear sample is an exact copy:
// 40 coalesced loads instead of 320 gathers. Wave-uniform branch.
// ----------------------------------------------------------------------------
__global__ __launch_bounds__(192) void warp_mlp2_tsplit_cf(
    const float* __restrict__ h,
    const float* __restrict__ theta,
    const float* __restrict__ W_T,
    const float* __restrict__ b_T,
    float* __restrict__ out) {
    __shared__ float red[64][41];   // stride 41 -> <=2 lanes/bank (free)
    int tid = threadIdx.x;
    int t = tid >> 6;               // wave index = temporal index
    int v = tid & 63;
    int b = blockIdx.x / (NVOX / 64);
    int vb = blockIdx.x % (NVOX / 64);
    int vid = vb * 64 + v;
    int w_ = vid % GY;              // Wp = 100
    int r2 = vid / GY;
    int h_ = r2 % GZ;               // Hp = 8
    int d_ = r2 / GZ;               // Dp = 100

    for (int i = tid; i < 64 * 41; i += 192) (&red[0][0])[i] = 0.f;
    __syncthreads();

    const float* ht = h + (size_t)(b * NT + t) * OC * NVOX;
    float sval[OC];

    if (t == 2) {
        // identity warp: exact copy of h[b][2][:, vid], fully coalesced
#pragma unroll
        for (int o = 0; o < OC; ++o) sval[o] = ht[(size_t)o * NVOX + vid];
    } else {
        float xg = -1.f + 2.f * (float)w_ / 99.f;
        float yg = -1.f + 2.f * (float)h_ / 7.f;
        float zg = -1.f + 2.f * (float)d_ / 99.f;

        const float* th = theta + (b * NT + t) * 12;
        float g0 = th[0] * xg + th[1] * yg + th[2] * zg + th[3];
        float g1 = th[4] * xg + th[5] * yg + th[6] * zg + th[7];
        float g2 = th[8] * xg + th[9] * yg + th[10] * zg + th[11];
        float ix = (g0 + 1.f) * 0.5f * 99.f;
        float iy = (g1 + 1.f) * 0.5f * 7.f;
        float iz = (g2 + 1.f) * 0.5f * 99.f;
        float x0 = floorf(ix), y0 = floorf(iy), z0 = floorf(iz);
        float wx1 = ix - x0, wy1 = iy - y0, wz1 = iz - z0;
        float wx0 = 1.f - wx1, wy0 = 1.f - wy1, wz0 = 1.f - wz1;

        float w8[8];
        int off8[8];
#pragma unroll
        for (int k = 0; k < 8; ++k) {
            float xf = x0 + (float)(k & 1);
            float yf = y0 + (float)((k >> 1) & 1);
            float zf = z0 + (float)(k >> 2);
            bool valid = (xf >= 0.f) & (xf <= 99.f) &
                         (yf >= 0.f) & (yf <= 7.f) &
                         (zf >= 0.f) & (zf <= 99.f);
            int xi = (int)fminf(fmaxf(xf, 0.f), 99.f);
            int yi = (int)fminf(fmaxf(yf, 0.f), 7.f);
            int zi = (int)fminf(fmaxf(zf, 0.f), 99.f);
            float w = ((k & 1) ? wx1 : wx0) * (((k >> 1) & 1) ? wy1 : wy0) *
                      ((k >> 2) ? wz1 : wz0);
            w8[k] = valid ? w : 0.f;
            off8[k] = (zi * GZ + yi) * GY + xi;
        }

        // coalesced gathers: sval[o] = sum_k w8[k] * h_t[o*NVOX + off8[k]]
#pragma unroll
        for (int o = 0; o < OC; ++o) {
            const float* ho = ht + (size_t)o * NVOX;
            float v0 = 0.f;
#pragma unroll
            for (int k = 0; k < 8; ++k) v0 = fmaf(w8[k], ho[off8[k]], v0);
            sval[o] = v0;
        }
    }

    // partial[o] = sum_o2 W_T[o, t*40 + o2] * sval[o2]; 4 outputs at a time
#pragma unroll
    for (int o = 0; o < OC; o += 4) {
        float p0 = 0.f, p1 = 0.f, p2 = 0.f, p3 = 0.f;
        const float4* w0 = reinterpret_cast<const float4*>(
            W_T + (o + 0) * (NT * OC) + t * OC);
        const float4* w1 = reinterpret_cast<const float4*>(
            W_T + (o + 1) * (NT * OC) + t * OC);
        const float4* w2 = reinterpret_cast<const float4*>(
            W_T + (o + 2) * (NT * OC) + t * OC);
        const float4* w3 = reinterpret_cast<const float4*>(
            W_T + (o + 3) * (NT * OC) + t * OC);
#pragma unroll
        for (int q = 0; q < 10; ++q) {
            float4 a0 = w0[q], a1 = w1[q], a2 = w2[q], a3 = w3[q];
            float s0 = sval[4 * q + 0], s1 = sval[4 * q + 1];
            float s2 = sval[4 * q + 2], s3 = sval[4 * q + 3];
            p0 = fmaf(a0.x, s0, p0); p0 = fmaf(a0.y, s1, p0);
            p0 = fmaf(a0.z, s2, p0); p0 = fmaf(a0.w, s3, p0);
            p1 = fmaf(a1.x, s0, p1); p1 = fmaf(a1.y, s1, p1);
            p1 = fmaf(a1.z, s2, p1); p1 = fmaf(a1.w, s3, p1);
            p2 = fmaf(a2.x, s0, p2); p2 = fmaf(a2.y, s1, p2);
            p2 = fmaf(a2.z, s2, p2); p2 = fmaf(a2.w, s3, p2);
            p3 = fmaf(a3.x, s0, p3); p3 = fmaf(a3.y, s1, p3);
            p3 = fmaf(a3.z, s2, p3); p3 = fmaf(a3.w, s3, p3);
        }
        atomicAdd(&red[v][o + 0], p0);
        atomicAdd(&red[v][o + 1], p1);
        atomicAdd(&red[v][o + 2], p2);
        atomicAdd(&red[v][o + 3], p3);
    }
    __syncthreads();

    // write out: 64 voxels x 40 outputs; coalesced rows of 64
    for (int idx = tid; idx < 64 * OC; idx += 192) {
        int o = idx >> 6;
        int vv = idx & 63;
        float val = red[vv][o] + b_T[o];
        out[((size_t)b * OC + o) * NVOX + (size_t)vb * 64 + vv] = fmaxf(val, 0.f);
    }
}

extern "C" void kernel_launch(void* const* d_in, const int* in_sizes, int n_in,
                              void* d_out, int out_size, void* d_ws, size_t ws_size,
                              hipStream_t stream) {
    const float* frustum = (const float*)d_in[0];
    const float* RT      = (const float*)d_in[1];
    const float* intrins = (const float*)d_in[2];
    const float* DoF     = (const float*)d_in[3];
    const float* W_N     = (const float*)d_in[4];
    const float* b_N     = (const float*)d_in[5];
    const float* W_T     = (const float*)d_in[6];
    const float* b_T     = (const float*)d_in[7];
    float* out = (float*)d_out;

    const size_t ft_f32 = FT_ELEMS * sizeof(float);   // ~170 MB
    const size_t h_f32  = HSZ * sizeof(float);        // ~77 MB
    const size_t small  = 4096;

    char* base = (char*)d_ws;
    const int tr_blocks = (NB * NT * NCAM * FSZ * 4) / 256;  // 41472
    const int n1_blocks = (NB * NT * NVOX) / 256;            // 1875
    const int n2_blocks = NB * (NVOX / 64);                  // 2500

    if (ws_size >= ft_f32 + h_f32 + small) {
        // fast path: fp32 channel-last features
        size_t ft_al = (ft_f32 + 255) & ~(size_t)255;
        float* ft_buf = (float*)base;
        float* h_buf = (float*)(base + ft_al);
        float* P_buf = (float*)(base + ft_al + ((h_f32 + 255) & ~(size_t)255));
        float* th_buf = P_buf + NB * NT * NCAM * 12;

        setup_kernel<<<1, 128, 0, stream>>>(RT, intrins, DoF, P_buf, th_buf);
        transpose_feat_f32_v2<<<tr_blocks, 256, 0, stream>>>(frustum, ft_buf);
        sample_mlp1_f32<true><<<n1_blocks, 256, 0, stream>>>(
            nullptr, ft_buf, P_buf, W_N, b_N, h_buf);
        warp_mlp2_tsplit_cf<<<n2_blocks, 192, 0, stream>>>(
            h_buf, th_buf, W_T, b_T, out);
    } else {
        // fallback: no feature transpose (original layout gathers)
        float* h_buf = (float*)base;
        float* P_buf = (float*)(base + ((h_f32 + 255) & ~(size_t)255));
        float* th_buf = P_buf + NB * NT * NCAM * 12;

        setup_kernel<<<1, 128, 0, stream>>>(RT, intrins, DoF, P_buf, th_buf);
        sample_mlp1_f32<false><<<n1_blocks, 256, 0, stream>>>(
            frustum, nullptr, P_buf, W_N, b_N, h_buf);
        warp_mlp2_tsplit_cf<<<n2_blocks, 192, 0, stream>>>(
            h_buf, th_buf, W_T, b_T, out);
    }
}